// Round 6
// baseline (142.428 us; speedup 1.0000x reference)
//
#include <hip/hip_runtime.h>
#include <hip/hip_bf16.h>

typedef __attribute__((ext_vector_type(4))) float f32x4;
typedef __attribute__((ext_vector_type(8))) short bf16x8;
typedef __attribute__((ext_vector_type(4))) short short4v;

#define ARS 72   // shorts per A-LDS row: 16 j * 4 comp + 8 pad = 144 B (16B-aligned; 36-dword stride -> 2-way max, free)
#define CS 132   // dwords per epilogue c row: 128 + 4 pad

__device__ __forceinline__ short f2bf(float f) {
  __hip_bfloat16 h = __float2bfloat16(f);
  return __builtin_bit_cast(short, h);
}

// ---------------------------------------------------------------------------
// GEMM view: C[8192 x 512] = A[8192 x 1024] * B[1024 x 512], k = j*4 + kc,
// kc -> x component {0,1,2,4}.
// Bp (d_ws, 1 MB): per-lane MFMA B-frag order Bp[it][cg][fc][lane][8 shorts].
//   cg = 64-point group (0..3); fc 0..3 -> c0 of points (fc&3)*16.., fc 4..7
//   -> c4 of the same points.  fc<4: {W0,W1,W2,0}; fc>=4: {0,W2,-W1,W0}.
// One frag load = 1 KB contiguous per wave (L2-hot).
// ---------------------------------------------------------------------------
__global__ __launch_bounds__(256) void ga_prep_B(const float* __restrict__ W,
                                                 short* __restrict__ Bp) {
  const int gid = blockIdx.x * 256 + threadIdx.x;  // 65536 = 32it*4cg*8fc*64l
  const int l  = gid & 63;
  const int fc = (gid >> 6) & 7;
  const int cg = (gid >> 9) & 3;
  const int it = gid >> 11;
  const int ln = l & 15, q = l >> 4;
  const int hc = fc >> 2;
  const int i  = cg * 64 + (fc & 3) * 16 + ln;
  const int j0 = it * 8 + q * 2;
  const float4* W4 = (const float4*)W;

  bf16x8 o;
#pragma unroll
  for (int jj = 0; jj < 2; ++jj) {
    const float4 wv = W4[((j0 + jj) * 256 + i) * 2];  // W[j][i][0..3]
    if (!hc) {
      o[jj * 4 + 0] = f2bf(wv.x); o[jj * 4 + 1] = f2bf(wv.y);
      o[jj * 4 + 2] = f2bf(wv.z); o[jj * 4 + 3] = 0;
    } else {
      o[jj * 4 + 0] = 0;           o[jj * 4 + 1] = f2bf(wv.z);
      o[jj * 4 + 2] = f2bf(-wv.y); o[jj * 4 + 3] = f2bf(wv.x);
    }
  }
  *(bf16x8*)&Bp[(size_t)gid * 8] = o;
}

// ---------------------------------------------------------------------------
// Main: 512 blocks = 128 row-tiles (M=64) x 4 cgs (128 GEMM cols = c0+c4 of
// 64 points -> full-32B multivector writes). 512 threads (8 waves; wave w
// owns frag-col fc=w), 2 blocks/CU. XCD swizzle: the 4 cg-blocks of one
// row-tile land on one XCD -> x served from L2 for 3 of 4.
// K in 16 slabs of 16 j (2 MFMA K-steps). Per slab: coalesced x stage
// (4 float4/thread, 512B runs) -> shuffle comp4 -> bf16 -> A_lds (double-
// buffered, 1 barrier/slab). B frags: depth-4 register ring from L2-hot Bp.
// ---------------------------------------------------------------------------
__global__ __launch_bounds__(512, 4) void ga_mv_main(
    const float* __restrict__ x, const short* __restrict__ Bp,
    const float* __restrict__ bias, float* __restrict__ y) {
  __shared__ __align__(16) char smem[33792];  // max(2*9216 A, 64*132*4 C)

  const int t = threadIdx.x;
  const int id = blockIdx.x;
  const int g = id & 7;
  const int cg = (id >> 3) & 3;
  const int bm = (id >> 5) * 8 + g;    // 0..127
  const int R0 = bm * 64;
  const int lane = t & 63, w = t >> 6;
  const int ln = lane & 15, qq = lane >> 4;

  short* Ab0 = (short*)smem;
  short* Ab1 = (short*)(smem + 9216);
  float* c_lds = (float*)smem;         // epilogue alias (A dead by then)

  // x staging map: slab s covers j 16s..16s+15 (32 float4 per row).
  // thread t: c32 = t&31 (float4-in-run), rows i*16 + (t>>5), i=0..3.
  const int c32 = t & 31, tb = t >> 5;
  const int h2 = t & 1;                // c32 parity: even -> comps0-3 owner
  const int jl = c32 >> 1;
  const float4* x4 = (const float4*)x;
  float4 fr[4];

#define LOADX(s)                                                            \
  {                                                                         \
    _Pragma("unroll")                                                       \
    for (int i = 0; i < 4; ++i)                                             \
      fr[i] = x4[(size_t)(R0 + i * 16 + tb) * 512 + (s) * 32 + c32];        \
  }

#define PROC(dst)                                                           \
  {                                                                         \
    _Pragma("unroll")                                                       \
    for (int i = 0; i < 4; ++i) {                                           \
      const float c4v = __shfl_xor(fr[i].x, 1, 64);                         \
      if (!h2) {                                                            \
        short4v a;                                                          \
        a[0] = f2bf(fr[i].x); a[1] = f2bf(fr[i].y);                         \
        a[2] = f2bf(fr[i].z); a[3] = f2bf(c4v);                             \
        *(short4v*)&(dst)[(i * 16 + tb) * ARS + jl * 4] = a;                \
      }                                                                     \
    }                                                                       \
  }

  // B frag ring (depth 4). Wave w's frag for K-step it:
  const short* bpw = Bp + ((size_t)cg * 8 + w) * 512 + lane * 8;
  bf16x8 Bf[4];
#define LB(itv) Bf[(itv) & 3] = *(const bf16x8*)(bpw + (size_t)(itv) * 32 * 512);

#define COMPUTE(Ac, tau, bfrag)                                             \
  {                                                                         \
    _Pragma("unroll")                                                       \
    for (int m = 0; m < 4; ++m) {                                           \
      const bf16x8 af =                                                     \
          *(const bf16x8*)&(Ac)[(m * 16 + ln) * ARS + (tau) * 32 + qq * 8]; \
      acc[m] = __builtin_amdgcn_mfma_f32_16x16x32_bf16(af, bfrag, acc[m],   \
                                                       0, 0, 0);            \
    }                                                                       \
  }

  f32x4 acc[4] = {};

  // ---- prologue ----
  LOADX(0);
  PROC(Ab0);       // waits slab-0 x once
  LOADX(1);        // in flight across slab 0
  LB(0); LB(1); LB(2); LB(3);
  __syncthreads();

#pragma unroll
  for (int s = 0; s < 16; ++s) {
    short* Ac = (s & 1) ? Ab1 : Ab0;
    short* An = (s & 1) ? Ab0 : Ab1;
    const int it0 = 2 * s;
    COMPUTE(Ac, 0, Bf[it0 & 3]);
    if (it0 + 4 < 32) LB(it0 + 4);
    if (s < 15) PROC(An);            // converts slab s+1 (loaded last slab)
    if (s < 14) LOADX(s + 2);        // ~full-slab latency cover
    COMPUTE(Ac, 1, Bf[(it0 + 1) & 3]);
    if (it0 + 5 < 32) LB(it0 + 5);   // L2-hot; small drain at barrier
    __syncthreads();                 // one barrier per slab
  }

  // ---- epilogue: acc -> c_lds (col = w*16+ln = h*64 + point), then
  // full-multivector contiguous y writes (2 KB runs) ----
  // C/D layout: col = ln, row = qq*4 + r
#pragma unroll
  for (int m = 0; m < 4; ++m)
#pragma unroll
    for (int r = 0; r < 4; ++r)
      c_lds[(m * 16 + qq * 4 + r) * CS + w * 16 + ln] = acc[m][r];
  __syncthreads();

  const int h = t & 1, p = (t >> 1) & 63, rr = t >> 7;  // rr 0..3
  const float4 bv = ((const float4*)bias)[(cg * 64 + p) * 2 + h];
  float4* y4 = (float4*)y;
#pragma unroll
  for (int r0 = 0; r0 < 16; ++r0) {
    const int row = r0 * 4 + rr;
    float4 o = bv;
    o.x += c_lds[row * CS + h * 64 + p];  // +c0 into comp0 / +c4 into comp4
    y4[((size_t)(R0 + row) * 256 + cg * 64 + p) * 2 + h] = o;
  }
}

extern "C" void kernel_launch(void* const* d_in, const int* in_sizes, int n_in,
                              void* d_out, int out_size, void* d_ws, size_t ws_size,
                              hipStream_t stream) {
  const float* x = (const float*)d_in[0];
  const float* W = (const float*)d_in[1];
  const float* bias = (const float*)d_in[2];
  float* y = (float*)d_out;
  short* Bp = (short*)d_ws;  // 32*4*8*64*16 = 1,048,576 B

  ga_prep_B<<<dim3(256), dim3(256), 0, stream>>>(W, Bp);
  ga_mv_main<<<dim3(512), dim3(512), 0, stream>>>(x, Bp, bias, y);
}